// Round 8
// baseline (247.937 us; speedup 1.0000x reference)
//
#include <hip/hip_runtime.h>
#include <hip/hip_bf16.h>

#define LOG2E 1.44269504088896340736f

typedef __attribute__((ext_vector_type(8))) short short8_t;   // 8 bf16 in 4 VGPRs
typedef __attribute__((ext_vector_type(4))) float f32x4_t;
typedef __attribute__((ext_vector_type(4))) unsigned short us4_t;

__device__ __forceinline__ unsigned short f2bf(float f) {
  unsigned u = __builtin_bit_cast(unsigned, f);
  return (unsigned short)((u + 0x7fffu + ((u >> 16) & 1u)) >> 16);
}

__device__ __forceinline__ void gload_lds16(const unsigned short* g, unsigned short* l) {
  __builtin_amdgcn_global_load_lds(
      (const __attribute__((address_space(1))) void*)(g),
      (__attribute__((address_space(3))) void*)(l), 16, 0, 0);
}

// ---------------------------------------------------------------- convert f32 -> bf16
__global__ __launch_bounds__(256) void cvt3(
    const float* __restrict__ x, const float* __restrict__ wq, const float* __restrict__ wo,
    unsigned short* __restrict__ xb, unsigned short* __restrict__ wqb,
    unsigned short* __restrict__ wob)
{
  const int n1 = 4096 * 1024 / 4, n2 = 3072 * 1024 / 4, n3 = 1024 * 1024 / 4;
  const int total = n1 + n2 + n3;
  for (int t = blockIdx.x * blockDim.x + threadIdx.x; t < total; t += gridDim.x * blockDim.x) {
    const float* s; unsigned short* d; int off;
    if (t < n1)            { s = x;  d = xb;  off = t * 4; }
    else if (t < n1 + n2)  { s = wq; d = wqb; off = (t - n1) * 4; }
    else                   { s = wo; d = wob; off = (t - n1 - n2) * 4; }
    f32x4_t v = *(const f32x4_t*)(s + off);
    us4_t o = { f2bf(v[0]), f2bf(v[1]), f2bf(v[2]), f2bf(v[3]) };
    *(us4_t*)(d + off) = o;
  }
}

// ---------------------------------------------------------------- bf16 GEMM, C = A * Bw^T + bias
// A: [M][K] bf16 row-major, Bw: [N][K] bf16 row-major.
// MODE 0: 128x128 tile, scatter-epilogue to Q/K [BH][L][64], Vt [BH][64][L]
// MODE 1: 128x64 tile (2 blocks/CU for the 4096x1024 out-proj), f32 out Cf[M][N]
// LDS layout: chunk-major [ck][rows][8] bf16 + 16-elem pad per chunk (8-bank
// shift between hi-groups). Staging via global_load_lds stays lane-linear:
// each wave's 64 slots lie inside one ck chunk.
template<int MODE>
__global__ __launch_bounds__(256) void gemm_bt(
    const unsigned short* __restrict__ A, const unsigned short* __restrict__ Bw,
    const float* __restrict__ bias, float* __restrict__ Cf,
    unsigned short* __restrict__ Qp, unsigned short* __restrict__ Kp,
    unsigned short* __restrict__ Vtp, int M, int N, int K)
{
  constexpr int BN   = (MODE == 0) ? 128 : 64;
  constexpr int NT_N = (MODE == 0) ? 24 : 16;    // N/BN
  constexpr int CPX  = (MODE == 0) ? 96 : 64;    // tiles per XCD (ntiles/8, exact)
  constexpr int ACK  = 1040;                      // A chunk stride: 128*8 + 16 pad
  constexpr int BCK  = (MODE == 0) ? 1040 : 528;  // B chunk stride

  __shared__ alignas(16) unsigned short lAl[4 * ACK];
  __shared__ alignas(16) unsigned short lBl[4 * BCK];

  const int tid = threadIdx.x, lane = tid & 63, w = tid >> 6;
  const int lo = lane & 15, hi = lane >> 4;

  // T1: bijective XCD swizzle (ntiles % 8 == 0 for both modes)
  const int lid = blockIdx.x;
  const int swz = (lid & 7) * CPX + (lid >> 3);
  const int bm = (swz / NT_N) * 128;
  const int bn = (swz % NT_N) * BN;

  const f32x4_t zero = {0.f, 0.f, 0.f, 0.f};
  constexpr int MI = (MODE == 0) ? 4 : 2;        // M frags per wave
  f32x4_t acc[MI][4];
#pragma unroll
  for (int i = 0; i < MI; ++i)
#pragma unroll
    for (int j = 0; j < 4; ++j) acc[i][j] = zero;

  // staging groups: slot s -> (ck = s/128, row = s%128); wave groups of 64
  // slots never cross a chunk boundary.
  const unsigned short* gA[2]; unsigned short* lAp[2];
#pragma unroll
  for (int i = 0; i < 2; ++i) {
    int s  = (i * 4 + w) * 64;                   // wave base slot
    int sl = s + lane;
    gA[i]  = &A[(size_t)(bm + (sl & 127)) * K + (sl >> 7) * 8];
    lAp[i] = &lAl[(s >> 7) * ACK + (s & 127) * 8];
  }
  const unsigned short* gB[2]; unsigned short* lBp[2];
  if (MODE == 0) {
#pragma unroll
    for (int i = 0; i < 2; ++i) {
      int s  = (i * 4 + w) * 64;
      int sl = s + lane;
      gB[i]  = &Bw[(size_t)(bn + (sl & 127)) * K + (sl >> 7) * 8];
      lBp[i] = &lBl[(s >> 7) * BCK + (s & 127) * 8];
    }
  } else {
    gB[0]  = &Bw[(size_t)(bn + lane) * K + w * 8]; // ck = w, row = lane
    lBp[0] = &lBl[w * BCK];
    gB[1]  = nullptr; lBp[1] = nullptr;
  }

  const int wm = (MODE == 0) ? (w >> 1) * 64 : w * 32;
  const int wn = (MODE == 0) ? (w & 1) * 64 : 0;

  for (int k0 = 0; k0 < K; k0 += 32) {
#pragma unroll
    for (int i = 0; i < 2; ++i) gload_lds16(gA[i] + k0, lAp[i]);
    if (MODE == 0) {
#pragma unroll
      for (int i = 0; i < 2; ++i) gload_lds16(gB[i] + k0, lBp[i]);
    } else {
      gload_lds16(gB[0] + k0, lBp[0]);
    }
    __syncthreads();                             // drains vmcnt before ds_read
    short8_t af[MI], bb[4];
#pragma unroll
    for (int i = 0; i < MI; ++i)
      af[i] = *(const short8_t*)&lAl[hi * ACK + (wm + i * 16 + lo) * 8];
#pragma unroll
    for (int j = 0; j < 4; ++j)
      bb[j] = *(const short8_t*)&lBl[hi * BCK + (wn + j * 16 + lo) * 8];
#pragma unroll
    for (int i = 0; i < MI; ++i)
#pragma unroll
      for (int j = 0; j < 4; ++j)
        acc[i][j] = __builtin_amdgcn_mfma_f32_16x16x32_bf16(af[i], bb[j], acc[i][j], 0, 0, 0);
    __syncthreads();
  }

  // epilogue: C/D layout col=lane&15, row=(lane>>4)*4+reg  [verified m89]
#pragma unroll
  for (int i = 0; i < MI; ++i) {
#pragma unroll
    for (int j = 0; j < 4; ++j) {
      int col = bn + wn + j * 16 + lo;
      float bv = bias[col];
#pragma unroll
      for (int r = 0; r < 4; ++r) {
        int row = bm + wm + i * 16 + hi * 4 + r;
        float v = acc[i][j][r] + bv;
        if (MODE == 1) {
          Cf[(size_t)row * N + col] = v;
        } else {
          unsigned short hv = f2bf(v);
          int sec = col >> 10, h = (col >> 6) & 15, d = col & 63;
          int b = row >> 11, ll = row & 2047;
          int bh = b * 16 + h;
          if (sec == 0)      Qp [((size_t)bh * 2048 + ll) * 64 + d] = hv;
          else if (sec == 1) Kp [((size_t)bh * 2048 + ll) * 64 + d] = hv;
          else               Vtp[((size_t)bh * 64 + d) * 2048 + ll] = hv;
        }
      }
    }
  }
}

// ---------------------------------------------------------------- causal flash attention v4
// (unchanged — K/V LDS-staged, double-buffered, LPT, defer-max)
__global__ __launch_bounds__(256) void attn(
    const unsigned short* __restrict__ Q, const unsigned short* __restrict__ K,
    const unsigned short* __restrict__ V, unsigned short* __restrict__ AO)
{
  const int tid = threadIdx.x, lane = tid & 63, w = tid >> 6;
  const int lo = lane & 15, hi = lane >> 4;
  const int qt = 31 - blockIdx.y;           // LPT: longest q-tiles dispatch first
  const int bh = blockIdx.x;
  const int qbase = qt * 64 + w * 16;
  const int nt = qt + 1;
  const unsigned short* Qb = Q + (size_t)bh * 2048 * 64;
  const unsigned short* Kb = K + (size_t)bh * 2048 * 64;
  const unsigned short* Vb = V + (size_t)bh * 64 * 2048;

  __shared__ alignas(16) unsigned short lK[2][8 * 512];
  __shared__ alignas(16) unsigned short lV[2][8 * 512];
  __shared__ alignas(16) unsigned short pl[4][16 * 72];
  unsigned short* myP = &pl[w][0];

  short8_t qf0 = *(const short8_t*)&Qb[(qbase + lo) * 64 + hi * 8];
  short8_t qf1 = *(const short8_t*)&Qb[(qbase + lo) * 64 + 32 + hi * 8];

  const f32x4_t zero = {0.f, 0.f, 0.f, 0.f};
  f32x4_t o[4] = {zero, zero, zero, zero};
  float m[4] = {-INFINITY, -INFINITY, -INFINITY, -INFINITY};
  float l[4] = {0.f, 0.f, 0.f, 0.f};
  const float SC = 0.125f * LOG2E;
  const float THR = 8.0f;

  const unsigned short* ksrc = Kb + (size_t)lane * 64 + 2 * w * 8;
  const unsigned short* vsrc = Vb + (size_t)lane * 2048 + 2 * w * 8;
  unsigned short* kd0 = &lK[0][2 * w * 512];
  unsigned short* kd1 = &lK[1][2 * w * 512];
  unsigned short* vd0 = &lV[0][2 * w * 512];
  unsigned short* vd1 = &lV[1][2 * w * 512];

  gload_lds16(ksrc,     kd0);
  gload_lds16(ksrc + 8, kd0 + 512);
  gload_lds16(vsrc,     vd0);
  gload_lds16(vsrc + 8, vd0 + 512);

  for (int t = 0; t < nt; ++t) {
    const int kb = t * 64;
    const int cur = t & 1;
    __syncthreads();

    if (t + 1 < nt) {
      const unsigned short* ks = ksrc + (size_t)(kb + 64) * 64;
      const unsigned short* vs = vsrc + (kb + 64);
      unsigned short* kd = cur ? kd0 : kd1;
      unsigned short* vd = cur ? vd0 : vd1;
      gload_lds16(ks,     kd);
      gload_lds16(ks + 8, kd + 512);
      gload_lds16(vs,     vd);
      gload_lds16(vs + 8, vd + 512);
    }
    const unsigned short* lk = cur ? &lK[1][0] : &lK[0][0];
    const unsigned short* lv = cur ? &lV[1][0] : &lV[0][0];

    f32x4_t s4[4] = {zero, zero, zero, zero};
    __builtin_amdgcn_s_setprio(1);
#pragma unroll
    for (int s = 0; s < 4; ++s) {
      short8_t k0 = *(const short8_t*)&lk[(hi * 64 + s * 16 + lo) * 8];
      short8_t k1 = *(const short8_t*)&lk[((4 + hi) * 64 + s * 16 + lo) * 8];
      s4[s] = __builtin_amdgcn_mfma_f32_16x16x32_bf16(qf0, k0, s4[s], 0, 0, 0);
      s4[s] = __builtin_amdgcn_mfma_f32_16x16x32_bf16(qf1, k1, s4[s], 0, 0, 0);
    }
    __builtin_amdgcn_s_setprio(0);

    const bool needmask = (kb + 64 > qbase);
    float a[4][4];
    float pm[4];
#pragma unroll
    for (int r = 0; r < 4; ++r) {
      int q = qbase + hi * 4 + r;
#pragma unroll
      for (int s = 0; s < 4; ++s) {
        float av = s4[s][r] * SC;
        if (needmask && (kb + s * 16 + lo > q)) av = -INFINITY;
        a[r][s] = av;
      }
      pm[r] = fmaxf(fmaxf(a[r][0], a[r][1]), fmaxf(a[r][2], a[r][3]));
    }

    bool ok = (pm[0] - m[0] <= THR) && (pm[1] - m[1] <= THR) &&
              (pm[2] - m[2] <= THR) && (pm[3] - m[3] <= THR);
    if (!__all(ok)) {
#pragma unroll
      for (int r = 0; r < 4; ++r) {
        float t2 = pm[r];
        t2 = fmaxf(t2, __shfl_xor(t2, 1));
        t2 = fmaxf(t2, __shfl_xor(t2, 2));
        t2 = fmaxf(t2, __shfl_xor(t2, 4));
        t2 = fmaxf(t2, __shfl_xor(t2, 8));
        float mn = fmaxf(m[r], t2);
        float f = __builtin_amdgcn_exp2f(m[r] - mn);
        m[r] = mn;
        l[r] *= f;
#pragma unroll
        for (int j = 0; j < 4; ++j) o[j][r] *= f;
      }
    }

#pragma unroll
    for (int r = 0; r < 4; ++r) {
      float e0 = __builtin_amdgcn_exp2f(a[r][0] - m[r]);
      float e1 = __builtin_amdgcn_exp2f(a[r][1] - m[r]);
      float e2 = __builtin_amdgcn_exp2f(a[r][2] - m[r]);
      float e3 = __builtin_amdgcn_exp2f(a[r][3] - m[r]);
      l[r] += (e0 + e1) + (e2 + e3);
      int prow = (hi * 4 + r) * 72;
      myP[prow + lo]      = f2bf(e0);
      myP[prow + 16 + lo] = f2bf(e1);
      myP[prow + 32 + lo] = f2bf(e2);
      myP[prow + 48 + lo] = f2bf(e3);
    }

    short8_t pf0 = *(const short8_t*)&myP[lo * 72 + hi * 8];
    short8_t pf1 = *(const short8_t*)&myP[lo * 72 + 32 + hi * 8];
    __builtin_amdgcn_s_setprio(1);
#pragma unroll
    for (int j = 0; j < 4; ++j) {
      short8_t v0 = *(const short8_t*)&lv[(hi * 64 + j * 16 + lo) * 8];
      short8_t v1 = *(const short8_t*)&lv[((4 + hi) * 64 + j * 16 + lo) * 8];
      o[j] = __builtin_amdgcn_mfma_f32_16x16x32_bf16(pf0, v0, o[j], 0, 0, 0);
      o[j] = __builtin_amdgcn_mfma_f32_16x16x32_bf16(pf1, v1, o[j], 0, 0, 0);
    }
    __builtin_amdgcn_s_setprio(0);
  }

  const int b = bh >> 4, h = bh & 15;
#pragma unroll
  for (int r = 0; r < 4; ++r) {
    float ls = l[r];
    ls += __shfl_xor(ls, 1);
    ls += __shfl_xor(ls, 2);
    ls += __shfl_xor(ls, 4);
    ls += __shfl_xor(ls, 8);
    float inv = 1.0f / ls;
    int qrow = qbase + hi * 4 + r;
    size_t base = ((size_t)b * 2048 + qrow) * 1024 + h * 64;
#pragma unroll
    for (int j = 0; j < 4; ++j)
      AO[base + j * 16 + lo] = f2bf(o[j][r] * inv);
  }
}

// ---------------------------------------------------------------- launch
extern "C" void kernel_launch(void* const* d_in, const int* in_sizes, int n_in,
                              void* d_out, int out_size, void* d_ws, size_t ws_size,
                              hipStream_t stream)
{
  (void)in_sizes; (void)n_in; (void)out_size; (void)ws_size;
  const float* x    = (const float*)d_in[0];
  const float* Wqkv = (const float*)d_in[2];
  const float* bqkv = (const float*)d_in[3];
  const float* Wout = (const float*)d_in[4];
  const float* bout = (const float*)d_in[5];

  unsigned short* ws  = (unsigned short*)d_ws;
  unsigned short* xb  = ws;                       // 4096*1024
  unsigned short* wqb = xb  + 4096 * 1024;        // 3072*1024
  unsigned short* wob = wqb + 3072 * 1024;        // 1024*1024
  unsigned short* Qp  = wob + 1024 * 1024;        // 32*2048*64
  unsigned short* Kp  = Qp  + 32 * 2048 * 64;
  unsigned short* Vtp = Kp  + 32 * 2048 * 64;
  unsigned short* AO  = Vtp + 32 * 2048 * 64;     // 4096*1024

  cvt3<<<dim3(2048), dim3(256), 0, stream>>>(x, Wqkv, Wout, xb, wqb, wob);
  gemm_bt<0><<<dim3(768), dim3(256), 0, stream>>>(
      xb, wqb, bqkv, nullptr, Qp, Kp, Vtp, 4096, 3072, 1024);
  attn<<<dim3(32, 32), dim3(256), 0, stream>>>(Qp, Kp, Vtp, AO);
  gemm_bt<1><<<dim3(512), dim3(256), 0, stream>>>(
      AO, wob, bout, (float*)d_out, nullptr, nullptr, nullptr, 4096, 1024, 1024);
}

// Round 9
// 226.715 us; speedup vs baseline: 1.0936x; 1.0936x over previous
//
#include <hip/hip_runtime.h>
#include <hip/hip_bf16.h>

#define LOG2E 1.44269504088896340736f

typedef __attribute__((ext_vector_type(8))) short short8_t;   // 8 bf16 in 4 VGPRs
typedef __attribute__((ext_vector_type(4))) float f32x4_t;
typedef __attribute__((ext_vector_type(4))) unsigned short us4_t;

__device__ __forceinline__ unsigned short f2bf(float f) {
  unsigned u = __builtin_bit_cast(unsigned, f);
  return (unsigned short)((u + 0x7fffu + ((u >> 16) & 1u)) >> 16);
}

__device__ __forceinline__ void gload_lds16(const unsigned short* g, unsigned short* l) {
  __builtin_amdgcn_global_load_lds(
      (const __attribute__((address_space(1))) void*)(g),
      (__attribute__((address_space(3))) void*)(l), 16, 0, 0);
}

// ---------------------------------------------------------------- convert f32 -> bf16
__global__ __launch_bounds__(256) void cvt3(
    const float* __restrict__ x, const float* __restrict__ wq, const float* __restrict__ wo,
    unsigned short* __restrict__ xb, unsigned short* __restrict__ wqb,
    unsigned short* __restrict__ wob)
{
  const int n1 = 4096 * 1024 / 4, n2 = 3072 * 1024 / 4, n3 = 1024 * 1024 / 4;
  const int total = n1 + n2 + n3;
  for (int t = blockIdx.x * blockDim.x + threadIdx.x; t < total; t += gridDim.x * blockDim.x) {
    const float* s; unsigned short* d; int off;
    if (t < n1)            { s = x;  d = xb;  off = t * 4; }
    else if (t < n1 + n2)  { s = wq; d = wqb; off = (t - n1) * 4; }
    else                   { s = wo; d = wob; off = (t - n1 - n2) * 4; }
    f32x4_t v = *(const f32x4_t*)(s + off);
    us4_t o = { f2bf(v[0]), f2bf(v[1]), f2bf(v[2]), f2bf(v[3]) };
    *(us4_t*)(d + off) = o;
  }
}

// ---------------------------------------------------------------- QKV GEMM (R6-proven config)
// 128x128 tile, A [M][K] bf16, Bw [N][K] bf16; scatter epilogue to
// Q [BH][L][64], K [BH][L][64], Vt [BH][64][L]. Grid (24, 32).
__global__ __launch_bounds__(256) void gemm_qkv(
    const unsigned short* __restrict__ A, const unsigned short* __restrict__ Bw,
    const float* __restrict__ bias,
    unsigned short* __restrict__ Qp, unsigned short* __restrict__ Kp,
    unsigned short* __restrict__ Vtp, int M, int N, int K)
{
  __shared__ alignas(16) unsigned short lA[128 * 32];
  __shared__ alignas(16) unsigned short lB[128 * 32];
  const int tid = threadIdx.x, lane = tid & 63, w = tid >> 6;
  const int lo = lane & 15, hi = lane >> 4;
  const int bm = blockIdx.y * 128, bn = blockIdx.x * 128;
  const int wm = (w >> 1) * 64, wn = (w & 1) * 64;

  const f32x4_t zero = {0.f, 0.f, 0.f, 0.f};
  f32x4_t acc[4][4];
#pragma unroll
  for (int i = 0; i < 4; ++i)
#pragma unroll
    for (int j = 0; j < 4; ++j) acc[i][j] = zero;

  const unsigned short* gA[2]; const unsigned short* gB[2];
  unsigned short* lAp[2]; unsigned short* lBp[2];
#pragma unroll
  for (int i = 0; i < 2; ++i) {
    int offb = (i * 4 + w) * 1024;        // wave-uniform byte base in 8KB tile
    int off  = offb + lane * 16;
    int row  = off >> 6;                  // 64B per row (32 bf16)
    int ke   = (off & 63) >> 1;
    gA[i]  = &A [(size_t)(bm + row) * K + ke];
    gB[i]  = &Bw[(size_t)(bn + row) * K + ke];
    lAp[i] = &lA[offb >> 1];
    lBp[i] = &lB[offb >> 1];
  }

  for (int k0 = 0; k0 < K; k0 += 32) {
#pragma unroll
    for (int i = 0; i < 2; ++i) {
      gload_lds16(gA[i] + k0, lAp[i]);
      gload_lds16(gB[i] + k0, lBp[i]);
    }
    __syncthreads();
    short8_t af[4], bb[4];
#pragma unroll
    for (int i = 0; i < 4; ++i) af[i] = *(const short8_t*)&lA[(wm + i * 16 + lo) * 32 + hi * 8];
#pragma unroll
    for (int j = 0; j < 4; ++j) bb[j] = *(const short8_t*)&lB[(wn + j * 16 + lo) * 32 + hi * 8];
#pragma unroll
    for (int i = 0; i < 4; ++i)
#pragma unroll
      for (int j = 0; j < 4; ++j)
        acc[i][j] = __builtin_amdgcn_mfma_f32_16x16x32_bf16(af[i], bb[j], acc[i][j], 0, 0, 0);
    __syncthreads();
  }

  // epilogue: C/D layout col=lane&15, row=(lane>>4)*4+reg  [verified m89]
#pragma unroll
  for (int i = 0; i < 4; ++i) {
#pragma unroll
    for (int j = 0; j < 4; ++j) {
      int col = bn + wn + j * 16 + lo;
      float bv = bias[col];
#pragma unroll
      for (int r = 0; r < 4; ++r) {
        int row = bm + wm + i * 16 + hi * 4 + r;
        float v = acc[i][j][r] + bv;
        unsigned short hv = f2bf(v);
        int sec = col >> 10, h = (col >> 6) & 15, d = col & 63;
        int b = row >> 11, ll = row & 2047;
        int bh = b * 16 + h;
        if (sec == 0)      Qp [((size_t)bh * 2048 + ll) * 64 + d] = hv;
        else if (sec == 1) Kp [((size_t)bh * 2048 + ll) * 64 + d] = hv;
        else               Vtp[((size_t)bh * 64 + d) * 2048 + ll] = hv;
      }
    }
  }
}

// ---------------------------------------------------------------- out-proj GEMM, 64x64 tiles
// 4 blocks/CU (1024 blocks) to overlap the per-step barrier chain.
// Wave w owns rows [w*16, w*16+16) x all 64 cols: acc[4] (N frags), 4 MFMA/step.
__global__ __launch_bounds__(256) void gemm_out(
    const unsigned short* __restrict__ A, const unsigned short* __restrict__ Bw,
    const float* __restrict__ bias, float* __restrict__ Cf, int M, int N, int K)
{
  __shared__ alignas(16) unsigned short lA[64 * 32];
  __shared__ alignas(16) unsigned short lB[64 * 32];
  const int tid = threadIdx.x, lane = tid & 63, w = tid >> 6;
  const int lo = lane & 15, hi = lane >> 4;
  const int bm = blockIdx.y * 64, bn = blockIdx.x * 64;

  const f32x4_t zero = {0.f, 0.f, 0.f, 0.f};
  f32x4_t acc[4] = {zero, zero, zero, zero};

  // staging: wave w covers quarter w of each 4KB tile (16 rows x 64B)
  const int off = w * 1024 + lane * 16;   // byte offset in tile
  const int row = off >> 6, ke = (off & 63) >> 1;
  const unsigned short* gA = &A [(size_t)(bm + row) * K + ke];
  const unsigned short* gB = &Bw[(size_t)(bn + row) * K + ke];
  unsigned short* lAp = &lA[(w * 1024) >> 1];
  unsigned short* lBp = &lB[(w * 1024) >> 1];

  for (int k0 = 0; k0 < K; k0 += 32) {
    gload_lds16(gA + k0, lAp);
    gload_lds16(gB + k0, lBp);
    __syncthreads();
    short8_t af = *(const short8_t*)&lA[(w * 16 + lo) * 32 + hi * 8];
    short8_t bb[4];
#pragma unroll
    for (int j = 0; j < 4; ++j) bb[j] = *(const short8_t*)&lB[(j * 16 + lo) * 32 + hi * 8];
#pragma unroll
    for (int j = 0; j < 4; ++j)
      acc[j] = __builtin_amdgcn_mfma_f32_16x16x32_bf16(af, bb[j], acc[j], 0, 0, 0);
    __syncthreads();
  }

#pragma unroll
  for (int j = 0; j < 4; ++j) {
    int col = bn + j * 16 + lo;
    float bv = bias[col];
#pragma unroll
    for (int r = 0; r < 4; ++r) {
      int row2 = bm + w * 16 + hi * 4 + r;
      Cf[(size_t)row2 * N + col] = acc[j][r] + bv;
    }
  }
}

// ---------------------------------------------------------------- causal flash attention v4
// (unchanged — K/V LDS-staged, double-buffered, LPT, defer-max)
__global__ __launch_bounds__(256) void attn(
    const unsigned short* __restrict__ Q, const unsigned short* __restrict__ K,
    const unsigned short* __restrict__ V, unsigned short* __restrict__ AO)
{
  const int tid = threadIdx.x, lane = tid & 63, w = tid >> 6;
  const int lo = lane & 15, hi = lane >> 4;
  const int qt = 31 - blockIdx.y;           // LPT: longest q-tiles dispatch first
  const int bh = blockIdx.x;
  const int qbase = qt * 64 + w * 16;
  const int nt = qt + 1;
  const unsigned short* Qb = Q + (size_t)bh * 2048 * 64;
  const unsigned short* Kb = K + (size_t)bh * 2048 * 64;
  const unsigned short* Vb = V + (size_t)bh * 64 * 2048;

  __shared__ alignas(16) unsigned short lK[2][8 * 512];
  __shared__ alignas(16) unsigned short lV[2][8 * 512];
  __shared__ alignas(16) unsigned short pl[4][16 * 72];
  unsigned short* myP = &pl[w][0];

  short8_t qf0 = *(const short8_t*)&Qb[(qbase + lo) * 64 + hi * 8];
  short8_t qf1 = *(const short8_t*)&Qb[(qbase + lo) * 64 + 32 + hi * 8];

  const f32x4_t zero = {0.f, 0.f, 0.f, 0.f};
  f32x4_t o[4] = {zero, zero, zero, zero};
  float m[4] = {-INFINITY, -INFINITY, -INFINITY, -INFINITY};
  float l[4] = {0.f, 0.f, 0.f, 0.f};
  const float SC = 0.125f * LOG2E;
  const float THR = 8.0f;

  const unsigned short* ksrc = Kb + (size_t)lane * 64 + 2 * w * 8;
  const unsigned short* vsrc = Vb + (size_t)lane * 2048 + 2 * w * 8;
  unsigned short* kd0 = &lK[0][2 * w * 512];
  unsigned short* kd1 = &lK[1][2 * w * 512];
  unsigned short* vd0 = &lV[0][2 * w * 512];
  unsigned short* vd1 = &lV[1][2 * w * 512];

  gload_lds16(ksrc,     kd0);
  gload_lds16(ksrc + 8, kd0 + 512);
  gload_lds16(vsrc,     vd0);
  gload_lds16(vsrc + 8, vd0 + 512);

  for (int t = 0; t < nt; ++t) {
    const int kb = t * 64;
    const int cur = t & 1;
    __syncthreads();

    if (t + 1 < nt) {
      const unsigned short* ks = ksrc + (size_t)(kb + 64) * 64;
      const unsigned short* vs = vsrc + (kb + 64);
      unsigned short* kd = cur ? kd0 : kd1;
      unsigned short* vd = cur ? vd0 : vd1;
      gload_lds16(ks,     kd);
      gload_lds16(ks + 8, kd + 512);
      gload_lds16(vs,     vd);
      gload_lds16(vs + 8, vd + 512);
    }
    const unsigned short* lk = cur ? &lK[1][0] : &lK[0][0];
    const unsigned short* lv = cur ? &lV[1][0] : &lV[0][0];

    f32x4_t s4[4] = {zero, zero, zero, zero};
    __builtin_amdgcn_s_setprio(1);
#pragma unroll
    for (int s = 0; s < 4; ++s) {
      short8_t k0 = *(const short8_t*)&lk[(hi * 64 + s * 16 + lo) * 8];
      short8_t k1 = *(const short8_t*)&lk[((4 + hi) * 64 + s * 16 + lo) * 8];
      s4[s] = __builtin_amdgcn_mfma_f32_16x16x32_bf16(qf0, k0, s4[s], 0, 0, 0);
      s4[s] = __builtin_amdgcn_mfma_f32_16x16x32_bf16(qf1, k1, s4[s], 0, 0, 0);
    }
    __builtin_amdgcn_s_setprio(0);

    const bool needmask = (kb + 64 > qbase);
    float a[4][4];
    float pm[4];
#pragma unroll
    for (int r = 0; r < 4; ++r) {
      int q = qbase + hi * 4 + r;
#pragma unroll
      for (int s = 0; s < 4; ++s) {
        float av = s4[s][r] * SC;
        if (needmask && (kb + s * 16 + lo > q)) av = -INFINITY;
        a[r][s] = av;
      }
      pm[r] = fmaxf(fmaxf(a[r][0], a[r][1]), fmaxf(a[r][2], a[r][3]));
    }

    bool ok = (pm[0] - m[0] <= THR) && (pm[1] - m[1] <= THR) &&
              (pm[2] - m[2] <= THR) && (pm[3] - m[3] <= THR);
    if (!__all(ok)) {
#pragma unroll
      for (int r = 0; r < 4; ++r) {
        float t2 = pm[r];
        t2 = fmaxf(t2, __shfl_xor(t2, 1));
        t2 = fmaxf(t2, __shfl_xor(t2, 2));
        t2 = fmaxf(t2, __shfl_xor(t2, 4));
        t2 = fmaxf(t2, __shfl_xor(t2, 8));
        float mn = fmaxf(m[r], t2);
        float f = __builtin_amdgcn_exp2f(m[r] - mn);
        m[r] = mn;
        l[r] *= f;
#pragma unroll
        for (int j = 0; j < 4; ++j) o[j][r] *= f;
      }
    }

#pragma unroll
    for (int r = 0; r < 4; ++r) {
      float e0 = __builtin_amdgcn_exp2f(a[r][0] - m[r]);
      float e1 = __builtin_amdgcn_exp2f(a[r][1] - m[r]);
      float e2 = __builtin_amdgcn_exp2f(a[r][2] - m[r]);
      float e3 = __builtin_amdgcn_exp2f(a[r][3] - m[r]);
      l[r] += (e0 + e1) + (e2 + e3);
      int prow = (hi * 4 + r) * 72;
      myP[prow + lo]      = f2bf(e0);
      myP[prow + 16 + lo] = f2bf(e1);
      myP[prow + 32 + lo] = f2bf(e2);
      myP[prow + 48 + lo] = f2bf(e3);
    }

    short8_t pf0 = *(const short8_t*)&myP[lo * 72 + hi * 8];
    short8_t pf1 = *(const short8_t*)&myP[lo * 72 + 32 + hi * 8];
    __builtin_amdgcn_s_setprio(1);
#pragma unroll
    for (int j = 0; j < 4; ++j) {
      short8_t v0 = *(const short8_t*)&lv[(hi * 64 + j * 16 + lo) * 8];
      short8_t v1 = *(const short8_t*)&lv[((4 + hi) * 64 + j * 16 + lo) * 8];
      o[j] = __builtin_amdgcn_mfma_f32_16x16x32_bf16(pf0, v0, o[j], 0, 0, 0);
      o[j] = __builtin_amdgcn_mfma_f32_16x16x32_bf16(pf1, v1, o[j], 0, 0, 0);
    }
    __builtin_amdgcn_s_setprio(0);
  }

  const int b = bh >> 4, h = bh & 15;
#pragma unroll
  for (int r = 0; r < 4; ++r) {
    float ls = l[r];
    ls += __shfl_xor(ls, 1);
    ls += __shfl_xor(ls, 2);
    ls += __shfl_xor(ls, 4);
    ls += __shfl_xor(ls, 8);
    float inv = 1.0f / ls;
    int qrow = qbase + hi * 4 + r;
    size_t base = ((size_t)b * 2048 + qrow) * 1024 + h * 64;
#pragma unroll
    for (int j = 0; j < 4; ++j)
      AO[base + j * 16 + lo] = f2bf(o[j][r] * inv);
  }
}

// ---------------------------------------------------------------- launch
extern "C" void kernel_launch(void* const* d_in, const int* in_sizes, int n_in,
                              void* d_out, int out_size, void* d_ws, size_t ws_size,
                              hipStream_t stream)
{
  (void)in_sizes; (void)n_in; (void)out_size; (void)ws_size;
  const float* x    = (const float*)d_in[0];
  const float* Wqkv = (const float*)d_in[2];
  const float* bqkv = (const float*)d_in[3];
  const float* Wout = (const float*)d_in[4];
  const float* bout = (const float*)d_in[5];

  unsigned short* ws  = (unsigned short*)d_ws;
  unsigned short* xb  = ws;                       // 4096*1024
  unsigned short* wqb = xb  + 4096 * 1024;        // 3072*1024
  unsigned short* wob = wqb + 3072 * 1024;        // 1024*1024
  unsigned short* Qp  = wob + 1024 * 1024;        // 32*2048*64
  unsigned short* Kp  = Qp  + 32 * 2048 * 64;
  unsigned short* Vtp = Kp  + 32 * 2048 * 64;
  unsigned short* AO  = Vtp + 32 * 2048 * 64;     // 4096*1024

  cvt3<<<dim3(2048), dim3(256), 0, stream>>>(x, Wqkv, Wout, xb, wqb, wob);
  gemm_qkv<<<dim3(24, 32), dim3(256), 0, stream>>>(
      xb, wqb, bqkv, Qp, Kp, Vtp, 4096, 3072, 1024);
  attn<<<dim3(32, 32), dim3(256), 0, stream>>>(Qp, Kp, Vtp, AO);
  gemm_out<<<dim3(16, 64), dim3(256), 0, stream>>>(
      AO, wob, bout, (float*)d_out, 4096, 1024, 1024);
}

// Round 10
// 215.677 us; speedup vs baseline: 1.1496x; 1.0512x over previous
//
#include <hip/hip_runtime.h>
#include <hip/hip_bf16.h>

#define LOG2E 1.44269504088896340736f

typedef __attribute__((ext_vector_type(8))) short short8_t;   // 8 bf16 in 4 VGPRs
typedef __attribute__((ext_vector_type(4))) float f32x4_t;
typedef __attribute__((ext_vector_type(4))) unsigned short us4_t;

__device__ __forceinline__ unsigned short f2bf(float f) {
  unsigned u = __builtin_bit_cast(unsigned, f);
  return (unsigned short)((u + 0x7fffu + ((u >> 16) & 1u)) >> 16);
}

__device__ __forceinline__ void gload_lds16(const unsigned short* g, unsigned short* l) {
  __builtin_amdgcn_global_load_lds(
      (const __attribute__((address_space(1))) void*)(g),
      (__attribute__((address_space(3))) void*)(l), 16, 0, 0);
}

// ---------------------------------------------------------------- convert f32 -> bf16
__global__ __launch_bounds__(256) void cvt3(
    const float* __restrict__ x, const float* __restrict__ wq, const float* __restrict__ wo,
    unsigned short* __restrict__ xb, unsigned short* __restrict__ wqb,
    unsigned short* __restrict__ wob)
{
  const int n1 = 4096 * 1024 / 4, n2 = 3072 * 1024 / 4, n3 = 1024 * 1024 / 4;
  const int total = n1 + n2 + n3;
  for (int t = blockIdx.x * blockDim.x + threadIdx.x; t < total; t += gridDim.x * blockDim.x) {
    const float* s; unsigned short* d; int off;
    if (t < n1)            { s = x;  d = xb;  off = t * 4; }
    else if (t < n1 + n2)  { s = wq; d = wqb; off = (t - n1) * 4; }
    else                   { s = wo; d = wob; off = (t - n1 - n2) * 4; }
    f32x4_t v = *(const f32x4_t*)(s + off);
    us4_t o = { f2bf(v[0]), f2bf(v[1]), f2bf(v[2]), f2bf(v[3]) };
    *(us4_t*)(d + off) = o;
  }
}

// ---------------------------------------------------------------- QKV GEMM, 128x128 tile, BK=64
// A [M][K] bf16, Bw [N][K] bf16; scatter epilogue to Q/K [BH][L][64], Vt [BH][64][L].
// LDS as two BK=32 subtiles [kc][row][32] (row stride 64B = proven bank profile).
// 16 K-steps, 2 barriers each (vs 32 x 2 at BK=32): half the drain points.
__global__ __launch_bounds__(256) void gemm_qkv(
    const unsigned short* __restrict__ A, const unsigned short* __restrict__ Bw,
    const float* __restrict__ bias,
    unsigned short* __restrict__ Qp, unsigned short* __restrict__ Kp,
    unsigned short* __restrict__ Vtp, int M, int N, int K)
{
  __shared__ alignas(16) unsigned short lA[2 * 128 * 32];
  __shared__ alignas(16) unsigned short lB[2 * 128 * 32];
  const int tid = threadIdx.x, lane = tid & 63, w = tid >> 6;
  const int lo = lane & 15, hi = lane >> 4;
  const int bm = blockIdx.y * 128, bn = blockIdx.x * 128;
  const int wm = (w >> 1) * 64, wn = (w & 1) * 64;

  const f32x4_t zero = {0.f, 0.f, 0.f, 0.f};
  f32x4_t acc[4][4];
#pragma unroll
  for (int i = 0; i < 4; ++i)
#pragma unroll
    for (int j = 0; j < 4; ++j) acc[i][j] = zero;

  // staging: 16 runs per operand; wave w owns runs {w + 4i}. Run r:
  // kc = r>>3, rowbase = (r&7)*16; lane: row = rowbase + lane/4, kf = (lane%4)*8.
  // Dest lane-linear within the run (1KB contiguous); global src per-lane.
  const unsigned short* gA[4]; const unsigned short* gB[4];
  unsigned short* lAp[4]; unsigned short* lBp[4];
#pragma unroll
  for (int i = 0; i < 4; ++i) {
    int r = w + i * 4;
    int kc = r >> 3, rowb = (r & 7) * 16;
    int row = rowb + (lane >> 2), kf = (lane & 3) * 8;
    gA[i]  = &A [(size_t)(bm + row) * K + kc * 32 + kf];
    gB[i]  = &Bw[(size_t)(bn + row) * K + kc * 32 + kf];
    lAp[i] = &lA[kc * 4096 + rowb * 32];
    lBp[i] = &lB[kc * 4096 + rowb * 32];
  }

  for (int k0 = 0; k0 < K; k0 += 64) {
#pragma unroll
    for (int i = 0; i < 4; ++i) {
      gload_lds16(gA[i] + k0, lAp[i]);
      gload_lds16(gB[i] + k0, lBp[i]);
    }
    __syncthreads();                       // drains vmcnt before ds_read
    short8_t af[2][4], bb[2][4];
#pragma unroll
    for (int kc = 0; kc < 2; ++kc) {
#pragma unroll
      for (int i = 0; i < 4; ++i) {
        af[kc][i] = *(const short8_t*)&lA[kc * 4096 + (wm + i * 16 + lo) * 32 + hi * 8];
        bb[kc][i] = *(const short8_t*)&lB[kc * 4096 + (wn + i * 16 + lo) * 32 + hi * 8];
      }
    }
#pragma unroll
    for (int kc = 0; kc < 2; ++kc)
#pragma unroll
      for (int i = 0; i < 4; ++i)
#pragma unroll
        for (int j = 0; j < 4; ++j)
          acc[i][j] = __builtin_amdgcn_mfma_f32_16x16x32_bf16(af[kc][i], bb[kc][j], acc[i][j], 0, 0, 0);
    __syncthreads();                       // compute done before next stage overwrites
  }

  // epilogue: C/D layout col=lane&15, row=(lane>>4)*4+reg  [verified m89]
#pragma unroll
  for (int i = 0; i < 4; ++i) {
#pragma unroll
    for (int j = 0; j < 4; ++j) {
      int col = bn + wn + j * 16 + lo;
      float bv = bias[col];
#pragma unroll
      for (int r = 0; r < 4; ++r) {
        int row = bm + wm + i * 16 + hi * 4 + r;
        float v = acc[i][j][r] + bv;
        unsigned short hv = f2bf(v);
        int sec = col >> 10, h = (col >> 6) & 15, d = col & 63;
        int b = row >> 11, ll = row & 2047;
        int bh = b * 16 + h;
        if (sec == 0)      Qp [((size_t)bh * 2048 + ll) * 64 + d] = hv;
        else if (sec == 1) Kp [((size_t)bh * 2048 + ll) * 64 + d] = hv;
        else               Vtp[((size_t)bh * 64 + d) * 2048 + ll] = hv;
      }
    }
  }
}

// ---------------------------------------------------------------- out-proj GEMM, 64x64 tiles, BK=64
// 4 blocks/CU (1024 blocks); 16 K-steps of 8 MFMA.
__global__ __launch_bounds__(256) void gemm_out(
    const unsigned short* __restrict__ A, const unsigned short* __restrict__ Bw,
    const float* __restrict__ bias, float* __restrict__ Cf, int M, int N, int K)
{
  __shared__ alignas(16) unsigned short lA[2 * 64 * 32];
  __shared__ alignas(16) unsigned short lB[2 * 64 * 32];
  const int tid = threadIdx.x, lane = tid & 63, w = tid >> 6;
  const int lo = lane & 15, hi = lane >> 4;
  const int bm = blockIdx.y * 64, bn = blockIdx.x * 64;

  const f32x4_t zero = {0.f, 0.f, 0.f, 0.f};
  f32x4_t acc[4] = {zero, zero, zero, zero};

  // staging: 8 runs per operand; wave w owns runs {w, w+4}. Run r:
  // kc = r>>2, rowbase = (r&3)*16.
  const unsigned short* gA[2]; const unsigned short* gB[2];
  unsigned short* lAp[2]; unsigned short* lBp[2];
#pragma unroll
  for (int i = 0; i < 2; ++i) {
    int r = w + i * 4;
    int kc = r >> 2, rowb = (r & 3) * 16;
    int row = rowb + (lane >> 2), kf = (lane & 3) * 8;
    gA[i]  = &A [(size_t)(bm + row) * K + kc * 32 + kf];
    gB[i]  = &Bw[(size_t)(bn + row) * K + kc * 32 + kf];
    lAp[i] = &lA[kc * 2048 + rowb * 32];
    lBp[i] = &lB[kc * 2048 + rowb * 32];
  }

  for (int k0 = 0; k0 < K; k0 += 64) {
#pragma unroll
    for (int i = 0; i < 2; ++i) {
      gload_lds16(gA[i] + k0, lAp[i]);
      gload_lds16(gB[i] + k0, lBp[i]);
    }
    __syncthreads();
    short8_t af[2], bb[2][4];
#pragma unroll
    for (int kc = 0; kc < 2; ++kc) {
      af[kc] = *(const short8_t*)&lA[kc * 2048 + (w * 16 + lo) * 32 + hi * 8];
#pragma unroll
      for (int j = 0; j < 4; ++j)
        bb[kc][j] = *(const short8_t*)&lB[kc * 2048 + (j * 16 + lo) * 32 + hi * 8];
    }
#pragma unroll
    for (int kc = 0; kc < 2; ++kc)
#pragma unroll
      for (int j = 0; j < 4; ++j)
        acc[j] = __builtin_amdgcn_mfma_f32_16x16x32_bf16(af[kc], bb[kc][j], acc[j], 0, 0, 0);
    __syncthreads();
  }

#pragma unroll
  for (int j = 0; j < 4; ++j) {
    int col = bn + j * 16 + lo;
    float bv = bias[col];
#pragma unroll
    for (int r = 0; r < 4; ++r) {
      int row2 = bm + w * 16 + hi * 4 + r;
      Cf[(size_t)row2 * N + col] = acc[j][r] + bv;
    }
  }
}

// ---------------------------------------------------------------- causal flash attention v4
// (unchanged — K/V LDS-staged, double-buffered, LPT, defer-max)
__global__ __launch_bounds__(256) void attn(
    const unsigned short* __restrict__ Q, const unsigned short* __restrict__ K,
    const unsigned short* __restrict__ V, unsigned short* __restrict__ AO)
{
  const int tid = threadIdx.x, lane = tid & 63, w = tid >> 6;
  const int lo = lane & 15, hi = lane >> 4;
  const int qt = 31 - blockIdx.y;           // LPT: longest q-tiles dispatch first
  const int bh = blockIdx.x;
  const int qbase = qt * 64 + w * 16;
  const int nt = qt + 1;
  const unsigned short* Qb = Q + (size_t)bh * 2048 * 64;
  const unsigned short* Kb = K + (size_t)bh * 2048 * 64;
  const unsigned short* Vb = V + (size_t)bh * 64 * 2048;

  __shared__ alignas(16) unsigned short lK[2][8 * 512];
  __shared__ alignas(16) unsigned short lV[2][8 * 512];
  __shared__ alignas(16) unsigned short pl[4][16 * 72];
  unsigned short* myP = &pl[w][0];

  short8_t qf0 = *(const short8_t*)&Qb[(qbase + lo) * 64 + hi * 8];
  short8_t qf1 = *(const short8_t*)&Qb[(qbase + lo) * 64 + 32 + hi * 8];

  const f32x4_t zero = {0.f, 0.f, 0.f, 0.f};
  f32x4_t o[4] = {zero, zero, zero, zero};
  float m[4] = {-INFINITY, -INFINITY, -INFINITY, -INFINITY};
  float l[4] = {0.f, 0.f, 0.f, 0.f};
  const float SC = 0.125f * LOG2E;
  const float THR = 8.0f;

  const unsigned short* ksrc = Kb + (size_t)lane * 64 + 2 * w * 8;
  const unsigned short* vsrc = Vb + (size_t)lane * 2048 + 2 * w * 8;
  unsigned short* kd0 = &lK[0][2 * w * 512];
  unsigned short* kd1 = &lK[1][2 * w * 512];
  unsigned short* vd0 = &lV[0][2 * w * 512];
  unsigned short* vd1 = &lV[1][2 * w * 512];

  gload_lds16(ksrc,     kd0);
  gload_lds16(ksrc + 8, kd0 + 512);
  gload_lds16(vsrc,     vd0);
  gload_lds16(vsrc + 8, vd0 + 512);

  for (int t = 0; t < nt; ++t) {
    const int kb = t * 64;
    const int cur = t & 1;
    __syncthreads();

    if (t + 1 < nt) {
      const unsigned short* ks = ksrc + (size_t)(kb + 64) * 64;
      const unsigned short* vs = vsrc + (kb + 64);
      unsigned short* kd = cur ? kd0 : kd1;
      unsigned short* vd = cur ? vd0 : vd1;
      gload_lds16(ks,     kd);
      gload_lds16(ks + 8, kd + 512);
      gload_lds16(vs,     vd);
      gload_lds16(vs + 8, vd + 512);
    }
    const unsigned short* lk = cur ? &lK[1][0] : &lK[0][0];
    const unsigned short* lv = cur ? &lV[1][0] : &lV[0][0];

    f32x4_t s4[4] = {zero, zero, zero, zero};
    __builtin_amdgcn_s_setprio(1);
#pragma unroll
    for (int s = 0; s < 4; ++s) {
      short8_t k0 = *(const short8_t*)&lk[(hi * 64 + s * 16 + lo) * 8];
      short8_t k1 = *(const short8_t*)&lk[((4 + hi) * 64 + s * 16 + lo) * 8];
      s4[s] = __builtin_amdgcn_mfma_f32_16x16x32_bf16(qf0, k0, s4[s], 0, 0, 0);
      s4[s] = __builtin_amdgcn_mfma_f32_16x16x32_bf16(qf1, k1, s4[s], 0, 0, 0);
    }
    __builtin_amdgcn_s_setprio(0);

    const bool needmask = (kb + 64 > qbase);
    float a[4][4];
    float pm[4];
#pragma unroll
    for (int r = 0; r < 4; ++r) {
      int q = qbase + hi * 4 + r;
#pragma unroll
      for (int s = 0; s < 4; ++s) {
        float av = s4[s][r] * SC;
        if (needmask && (kb + s * 16 + lo > q)) av = -INFINITY;
        a[r][s] = av;
      }
      pm[r] = fmaxf(fmaxf(a[r][0], a[r][1]), fmaxf(a[r][2], a[r][3]));
    }

    bool ok = (pm[0] - m[0] <= THR) && (pm[1] - m[1] <= THR) &&
              (pm[2] - m[2] <= THR) && (pm[3] - m[3] <= THR);
    if (!__all(ok)) {
#pragma unroll
      for (int r = 0; r < 4; ++r) {
        float t2 = pm[r];
        t2 = fmaxf(t2, __shfl_xor(t2, 1));
        t2 = fmaxf(t2, __shfl_xor(t2, 2));
        t2 = fmaxf(t2, __shfl_xor(t2, 4));
        t2 = fmaxf(t2, __shfl_xor(t2, 8));
        float mn = fmaxf(m[r], t2);
        float f = __builtin_amdgcn_exp2f(m[r] - mn);
        m[r] = mn;
        l[r] *= f;
#pragma unroll
        for (int j = 0; j < 4; ++j) o[j][r] *= f;
      }
    }

#pragma unroll
    for (int r = 0; r < 4; ++r) {
      float e0 = __builtin_amdgcn_exp2f(a[r][0] - m[r]);
      float e1 = __builtin_amdgcn_exp2f(a[r][1] - m[r]);
      float e2 = __builtin_amdgcn_exp2f(a[r][2] - m[r]);
      float e3 = __builtin_amdgcn_exp2f(a[r][3] - m[r]);
      l[r] += (e0 + e1) + (e2 + e3);
      int prow = (hi * 4 + r) * 72;
      myP[prow + lo]      = f2bf(e0);
      myP[prow + 16 + lo] = f2bf(e1);
      myP[prow + 32 + lo] = f2bf(e2);
      myP[prow + 48 + lo] = f2bf(e3);
    }

    short8_t pf0 = *(const short8_t*)&myP[lo * 72 + hi * 8];
    short8_t pf1 = *(const short8_t*)&myP[lo * 72 + 32 + hi * 8];
    __builtin_amdgcn_s_setprio(1);
#pragma unroll
    for (int j = 0; j < 4; ++j) {
      short8_t v0 = *(const short8_t*)&lv[(hi * 64 + j * 16 + lo) * 8];
      short8_t v1 = *(const short8_t*)&lv[((4 + hi) * 64 + j * 16 + lo) * 8];
      o[j] = __builtin_amdgcn_mfma_f32_16x16x32_bf16(pf0, v0, o[j], 0, 0, 0);
      o[j] = __builtin_amdgcn_mfma_f32_16x16x32_bf16(pf1, v1, o[j], 0, 0, 0);
    }
    __builtin_amdgcn_s_setprio(0);
  }

  const int b = bh >> 4, h = bh & 15;
#pragma unroll
  for (int r = 0; r < 4; ++r) {
    float ls = l[r];
    ls += __shfl_xor(ls, 1);
    ls += __shfl_xor(ls, 2);
    ls += __shfl_xor(ls, 4);
    ls += __shfl_xor(ls, 8);
    float inv = 1.0f / ls;
    int qrow = qbase + hi * 4 + r;
    size_t base = ((size_t)b * 2048 + qrow) * 1024 + h * 64;
#pragma unroll
    for (int j = 0; j < 4; ++j)
      AO[base + j * 16 + lo] = f2bf(o[j][r] * inv);
  }
}

// ---------------------------------------------------------------- launch
extern "C" void kernel_launch(void* const* d_in, const int* in_sizes, int n_in,
                              void* d_out, int out_size, void* d_ws, size_t ws_size,
                              hipStream_t stream)
{
  (void)in_sizes; (void)n_in; (void)out_size; (void)ws_size;
  const float* x    = (const float*)d_in[0];
  const float* Wqkv = (const float*)d_in[2];
  const float* bqkv = (const float*)d_in[3];
  const float* Wout = (const float*)d_in[4];
  const float* bout = (const float*)d_in[5];

  unsigned short* ws  = (unsigned short*)d_ws;
  unsigned short* xb  = ws;                       // 4096*1024
  unsigned short* wqb = xb  + 4096 * 1024;        // 3072*1024
  unsigned short* wob = wqb + 3072 * 1024;        // 1024*1024
  unsigned short* Qp  = wob + 1024 * 1024;        // 32*2048*64
  unsigned short* Kp  = Qp  + 32 * 2048 * 64;
  unsigned short* Vtp = Kp  + 32 * 2048 * 64;
  unsigned short* AO  = Vtp + 32 * 2048 * 64;     // 4096*1024

  cvt3<<<dim3(2048), dim3(256), 0, stream>>>(x, Wqkv, Wout, xb, wqb, wob);
  gemm_qkv<<<dim3(24, 32), dim3(256), 0, stream>>>(
      xb, wqb, bqkv, Qp, Kp, Vtp, 4096, 3072, 1024);
  attn<<<dim3(32, 32), dim3(256), 0, stream>>>(Qp, Kp, Vtp, AO);
  gemm_out<<<dim3(16, 64), dim3(256), 0, stream>>>(
      AO, wob, bout, (float*)d_out, 4096, 1024, 1024);
}